// Round 1
// baseline (553.604 us; speedup 1.0000x reference)
//
#include <hip/hip_runtime.h>

#define N_NODES 50000
#define E_EDGES 1600000
#define IN_F    128
#define OUT_F   64
#define ALPHA   0.2f

// ---------------------------------------------------------------------------
// Kernel A: h = X @ W  (row per 64-lane wave, lane = output feature),
// fused epilogue: s_src[row] = h[row,:].a[:64], s_dst[row] = h[row,:].a[64:]
// ---------------------------------------------------------------------------
__global__ void __launch_bounds__(256)
gat_gemm_scores(const float* __restrict__ x, const float* __restrict__ W,
                const float* __restrict__ a, float* __restrict__ h,
                float* __restrict__ s_src, float* __restrict__ s_dst) {
    int row = blockIdx.x * 4 + (threadIdx.x >> 6);
    int f   = threadIdx.x & 63;
    if (row >= N_NODES) return;

    const float* xr = x + (long long)row * IN_F;
    float acc = 0.f;
#pragma unroll 8
    for (int k = 0; k < IN_F; ++k)
        acc += xr[k] * W[k * OUT_F + f];   // xr[k] wave-broadcast, W coalesced

    h[(long long)row * OUT_F + f] = acc;

    float ps = acc * a[f];
    float pd = acc * a[OUT_F + f];
#pragma unroll
    for (int off = 32; off > 0; off >>= 1) {
        ps += __shfl_xor(ps, off, 64);
        pd += __shfl_xor(pd, off, 64);
    }
    if (f == 0) { s_src[row] = ps; s_dst[row] = pd; }
}

// ---------------------------------------------------------------------------
// Kernel B: per-edge attention weight + rowsum atomic
// ---------------------------------------------------------------------------
__global__ void __launch_bounds__(256)
gat_edge(const int* __restrict__ esrc, const int* __restrict__ edst,
         const float* __restrict__ s_src, const float* __restrict__ s_dst,
         float* __restrict__ edge_e, float* __restrict__ rowsum) {
    int e = blockIdx.x * blockDim.x + threadIdx.x;
    if (e >= E_EDGES) return;
    int s = esrc[e];
    int d = edst[e];
    float sc = s_src[s] + s_dst[d];
    float lr = sc > 0.f ? sc : ALPHA * sc;
    float ee = __expf(-lr);
    edge_e[e] = ee;
    atomicAdd(&rowsum[s], ee);
}

// ---------------------------------------------------------------------------
// Kernel C: scatter h_prime[src,f] += e * h[dst,f].  One wave per edge
// (lane = feature). Accumulates directly into d_out (pre-zeroed).
// ---------------------------------------------------------------------------
__global__ void __launch_bounds__(256)
gat_scatter(const int* __restrict__ esrc, const int* __restrict__ edst,
            const float* __restrict__ edge_e, const float* __restrict__ h,
            float* __restrict__ out) {
    long long idx = (long long)blockIdx.x * blockDim.x + threadIdx.x;
    int e = (int)(idx >> 6);
    int f = (int)(idx & 63);
    if (e >= E_EDGES) return;
    float ee = edge_e[e];          // wave-broadcast
    int s = esrc[e];               // wave-broadcast
    int d = edst[e];               // wave-broadcast
    atomicAdd(&out[(long long)s * OUT_F + f], ee * h[(long long)d * OUT_F + f]);
}

// ---------------------------------------------------------------------------
// Kernel D: out = elu(out / rowsum)  in place
// ---------------------------------------------------------------------------
__global__ void __launch_bounds__(256)
gat_finalize(const float* __restrict__ rowsum, float* __restrict__ out) {
    int idx = blockIdx.x * blockDim.x + threadIdx.x;
    if (idx >= N_NODES * OUT_F) return;
    int row = idx >> 6;
    float v = out[idx] / rowsum[row];
    out[idx] = v > 0.f ? v : (__expf(v) - 1.f);
}

// ---------------------------------------------------------------------------
extern "C" void kernel_launch(void* const* d_in, const int* in_sizes, int n_in,
                              void* d_out, int out_size, void* d_ws, size_t ws_size,
                              hipStream_t stream) {
    const float* x    = (const float*)d_in[0];
    const int*   edge = (const int*)d_in[1];   // (2, E) int32, row-major
    const float* W    = (const float*)d_in[2];
    const float* a    = (const float*)d_in[3];
    float*       out  = (float*)d_out;

    const int* esrc = edge;
    const int* edst = edge + E_EDGES;

    char* ws = (char*)d_ws;
    float* h      = (float*)ws;                                   // N*64 f32 = 12.8 MB
    float* s_src  = (float*)(ws + (size_t)N_NODES * OUT_F * 4);   // N f32
    float* s_dst  = s_src + N_NODES;                              // N f32
    float* rowsum = s_dst + N_NODES;                              // N f32
    float* edge_e = rowsum + N_NODES;                             // E f32 = 6.4 MB

    // Zero accumulators every call (harness poisons once, never re-poisons).
    hipMemsetAsync(out, 0, (size_t)N_NODES * OUT_F * sizeof(float), stream);
    hipMemsetAsync(rowsum, 0, (size_t)N_NODES * sizeof(float), stream);

    gat_gemm_scores<<<(N_NODES + 3) / 4, 256, 0, stream>>>(x, W, a, h, s_src, s_dst);

    gat_edge<<<(E_EDGES + 255) / 256, 256, 0, stream>>>(esrc, edst, s_src, s_dst,
                                                        edge_e, rowsum);

    long long total = (long long)E_EDGES * OUT_F;
    gat_scatter<<<(int)((total + 255) / 256), 256, 0, stream>>>(esrc, edst, edge_e,
                                                                h, out);

    gat_finalize<<<(N_NODES * OUT_F + 255) / 256, 256, 0, stream>>>(rowsum, out);
}

// Round 2
// 311.900 us; speedup vs baseline: 1.7749x; 1.7749x over previous
//
#include <hip/hip_runtime.h>
#include <hip/hip_bf16.h>

#define N_NODES 50000
#define E_EDGES 1600000
#define IN_F    128
#define OUT_F   64
#define ALPHA   0.2f
#define NB_SCAN 196          // ceil(50000/256)

// ---------------------------------------------------------------------------
// K1: h = X @ W (bf16 out), fused s_src/s_dst epilogue.
// One wave per row; row of x held in 2 VGPRs, broadcast via __shfl with
// constant lane index (unrolled -> v_readlane). W (32KB) stays L1-resident.
// ---------------------------------------------------------------------------
__global__ void __launch_bounds__(256)
gat_gemm_scores(const float* __restrict__ x, const float* __restrict__ W,
                const float* __restrict__ a,
                __hip_bfloat16* __restrict__ hb,
                float* __restrict__ s_src, float* __restrict__ s_dst) {
    int w = threadIdx.x >> 6, f = threadIdx.x & 63;
    int row = blockIdx.x * 4 + w;                 // 12500 blocks exactly
    const float* xr = x + (size_t)row * IN_F;
    float xv0 = xr[f];
    float xv1 = xr[64 + f];
    float acc = 0.f;
#pragma unroll
    for (int k = 0; k < 64; ++k)
        acc += __shfl(xv0, k, 64) * W[k * OUT_F + f];
#pragma unroll
    for (int k = 0; k < 64; ++k)
        acc += __shfl(xv1, k, 64) * W[(64 + k) * OUT_F + f];

    hb[(size_t)row * OUT_F + f] = (__hip_bfloat16)acc;

    float ps = acc * a[f];
    float pd = acc * a[OUT_F + f];
#pragma unroll
    for (int off = 32; off > 0; off >>= 1) {
        ps += __shfl_xor(ps, off, 64);
        pd += __shfl_xor(pd, off, 64);
    }
    if (f == 0) { s_src[row] = ps; s_dst[row] = pd; }
}

// ---------------------------------------------------------------------------
// K2: out-degree histogram (int atomics), int4 edge loads
// ---------------------------------------------------------------------------
__global__ void __launch_bounds__(256)
gat_degree(const int4* __restrict__ esrc4, int* __restrict__ deg) {
    int i = blockIdx.x * 256 + threadIdx.x;
    if (i < E_EDGES / 4) {
        int4 v = esrc4[i];
        atomicAdd(&deg[v.x], 1);
        atomicAdd(&deg[v.y], 1);
        atomicAdd(&deg[v.z], 1);
        atomicAdd(&deg[v.w], 1);
    }
}

// ---------------------------------------------------------------------------
// K3a/b/c: exclusive prefix sum over deg -> rowptr
// ---------------------------------------------------------------------------
__global__ void __launch_bounds__(256)
scan_block_reduce(const int* __restrict__ deg, int* __restrict__ bsum) {
    int i = blockIdx.x * 256 + threadIdx.x;
    int v = (i < N_NODES) ? deg[i] : 0;
#pragma unroll
    for (int off = 32; off > 0; off >>= 1) v += __shfl_xor(v, off, 64);
    __shared__ int s[4];
    if ((threadIdx.x & 63) == 0) s[threadIdx.x >> 6] = v;
    __syncthreads();
    if (threadIdx.x == 0) bsum[blockIdx.x] = s[0] + s[1] + s[2] + s[3];
}

__global__ void __launch_bounds__(256)
scan_top(const int* __restrict__ bsum, int* __restrict__ boff) {
    __shared__ int s[256];
    int t = threadIdx.x;
    int v = (t < NB_SCAN) ? bsum[t] : 0;
    s[t] = v;
    __syncthreads();
    for (int d = 1; d < 256; d <<= 1) {
        int add = (t >= d) ? s[t - d] : 0;
        __syncthreads();
        s[t] += add;
        __syncthreads();
    }
    if (t < NB_SCAN) boff[t] = s[t] - v;          // exclusive
}

__global__ void __launch_bounds__(256)
scan_apply(const int* __restrict__ deg, const int* __restrict__ boff,
           int* __restrict__ rowptr) {
    int t = threadIdx.x;
    int i = blockIdx.x * 256 + t;
    __shared__ int s[256];
    int v = (i < N_NODES) ? deg[i] : 0;
    s[t] = v;
    __syncthreads();
    for (int d = 1; d < 256; d <<= 1) {
        int add = (t >= d) ? s[t - d] : 0;
        __syncthreads();
        s[t] += add;
        __syncthreads();
    }
    if (i < N_NODES) rowptr[i] = boff[blockIdx.x] + s[t] - v;  // exclusive
    if (i == 0) rowptr[N_NODES] = E_EDGES;
}

// ---------------------------------------------------------------------------
// K4: per-edge attention weight + bucket into CSR slot
// ---------------------------------------------------------------------------
__global__ void __launch_bounds__(256)
gat_edge_scatter(const int* __restrict__ esrc, const int* __restrict__ edst,
                 const float* __restrict__ s_src, const float* __restrict__ s_dst,
                 const int* __restrict__ rowptr, int* __restrict__ cnt,
                 int* __restrict__ dst_sorted, float* __restrict__ ee_sorted) {
    int e = blockIdx.x * 256 + threadIdx.x;
    if (e >= E_EDGES) return;
    int s = esrc[e];
    int d = edst[e];
    float sc = s_src[s] + s_dst[d];
    float lr = sc > 0.f ? sc : ALPHA * sc;
    float ee = __expf(-lr);
    int pos = rowptr[s] + atomicAdd(&cnt[s], 1);
    dst_sorted[pos] = d;
    ee_sorted[pos]  = ee;
}

// ---------------------------------------------------------------------------
// K5: per-node segment reduction. One wave per node, lane = feature.
// 4x unrolled so 4 independent h-gathers are in flight per wave.
// Finalize (divide + elu) fused; writes out exactly once -> no out memset.
// ---------------------------------------------------------------------------
__global__ void __launch_bounds__(256)
gat_aggregate(const int* __restrict__ rowptr, const int* __restrict__ dst_sorted,
              const float* __restrict__ ee_sorted,
              const __hip_bfloat16* __restrict__ hb, float* __restrict__ out) {
    int node = blockIdx.x * 4 + (threadIdx.x >> 6);   // 12500 blocks
    int f = threadIdx.x & 63;
    int beg = rowptr[node];
    int end = rowptr[node + 1];
    float acc = 0.f, rs = 0.f;
    int j = beg;
    for (; j + 3 < end; j += 4) {
        int   d0 = dst_sorted[j],     d1 = dst_sorted[j + 1];
        int   d2 = dst_sorted[j + 2], d3 = dst_sorted[j + 3];
        float e0 = ee_sorted[j],      e1 = ee_sorted[j + 1];
        float e2 = ee_sorted[j + 2],  e3 = ee_sorted[j + 3];
        float h0 = (float)hb[(size_t)d0 * OUT_F + f];
        float h1 = (float)hb[(size_t)d1 * OUT_F + f];
        float h2 = (float)hb[(size_t)d2 * OUT_F + f];
        float h3 = (float)hb[(size_t)d3 * OUT_F + f];
        acc += e0 * h0 + e1 * h1 + e2 * h2 + e3 * h3;
        rs  += e0 + e1 + e2 + e3;
    }
    for (; j < end; ++j) {
        float ee = ee_sorted[j];
        int   d  = dst_sorted[j];
        acc += ee * (float)hb[(size_t)d * OUT_F + f];
        rs  += ee;
    }
    float v = (rs != 0.f) ? acc / rs : 0.f;
    out[(size_t)node * OUT_F + f] = v > 0.f ? v : (__expf(v) - 1.f);
}

// ---------------------------------------------------------------------------
extern "C" void kernel_launch(void* const* d_in, const int* in_sizes, int n_in,
                              void* d_out, int out_size, void* d_ws, size_t ws_size,
                              hipStream_t stream) {
    const float* x    = (const float*)d_in[0];
    const int*   edge = (const int*)d_in[1];   // (2, E) int32 row-major
    const float* W    = (const float*)d_in[2];
    const float* a    = (const float*)d_in[3];
    float*       out  = (float*)d_out;

    const int* esrc = edge;
    const int* edst = edge + E_EDGES;

    char* ws = (char*)d_ws;
    size_t off = 0;
    __hip_bfloat16* hb = (__hip_bfloat16*)(ws + off); off += (size_t)N_NODES * OUT_F * 2; // 6.4MB
    float* s_src  = (float*)(ws + off); off += (size_t)N_NODES * 4;
    float* s_dst  = (float*)(ws + off); off += (size_t)N_NODES * 4;
    int*   deg    = (int*)  (ws + off); off += (size_t)N_NODES * 4;
    int*   cnt    = (int*)  (ws + off); off += (size_t)N_NODES * 4;
    int*   rowptr = (int*)  (ws + off); off += (size_t)(N_NODES + 1) * 4;
    int*   bsum   = (int*)  (ws + off); off += 256 * 4;
    int*   boff   = (int*)  (ws + off); off += 256 * 4;
    int*   dst_sorted = (int*)  (ws + off); off += (size_t)E_EDGES * 4;   // 6.4MB
    float* ee_sorted  = (float*)(ws + off); off += (size_t)E_EDGES * 4;   // 6.4MB

    hipMemsetAsync(deg, 0, (size_t)N_NODES * 4, stream);
    hipMemsetAsync(cnt, 0, (size_t)N_NODES * 4, stream);

    gat_gemm_scores<<<N_NODES / 4, 256, 0, stream>>>(x, W, a, hb, s_src, s_dst);

    gat_degree<<<(E_EDGES / 4 + 255) / 256, 256, 0, stream>>>((const int4*)esrc, deg);

    scan_block_reduce<<<NB_SCAN, 256, 0, stream>>>(deg, bsum);
    scan_top<<<1, 256, 0, stream>>>(bsum, boff);
    scan_apply<<<NB_SCAN, 256, 0, stream>>>(deg, boff, rowptr);

    gat_edge_scatter<<<E_EDGES / 256, 256, 0, stream>>>(esrc, edst, s_src, s_dst,
                                                        rowptr, cnt, dst_sorted,
                                                        ee_sorted);

    gat_aggregate<<<N_NODES / 4, 256, 0, stream>>>(rowptr, dst_sorted, ee_sorted,
                                                   hb, out);
}

// Round 3
// 297.975 us; speedup vs baseline: 1.8579x; 1.0467x over previous
//
#include <hip/hip_runtime.h>
#include <hip/hip_bf16.h>

#define N_NODES 50000
#define E_EDGES 1600000
#define IN_F    128
#define OUT_F   64
#define ALPHA   0.2f
#define NB_SCAN 196          // ceil(50000/256)

// ---------------------------------------------------------------------------
// K1: h = X @ W (bf16 out), fused s_src/s_dst epilogue.
// One wave per row; row of x held in 2 VGPRs, broadcast via __shfl with
// constant lane index (unrolled -> v_readlane). W (32KB) stays L1-resident.
// ---------------------------------------------------------------------------
__global__ void __launch_bounds__(256)
gat_gemm_scores(const float* __restrict__ x, const float* __restrict__ W,
                const float* __restrict__ a,
                __hip_bfloat16* __restrict__ hb,
                float* __restrict__ s_src, float* __restrict__ s_dst) {
    int w = threadIdx.x >> 6, f = threadIdx.x & 63;
    int row = blockIdx.x * 4 + w;                 // 12500 blocks exactly
    const float* xr = x + (size_t)row * IN_F;
    float xv0 = xr[f];
    float xv1 = xr[64 + f];
    float acc = 0.f;
#pragma unroll
    for (int k = 0; k < 64; ++k)
        acc += __shfl(xv0, k, 64) * W[k * OUT_F + f];
#pragma unroll
    for (int k = 0; k < 64; ++k)
        acc += __shfl(xv1, k, 64) * W[(64 + k) * OUT_F + f];

    hb[(size_t)row * OUT_F + f] = (__hip_bfloat16)acc;

    float ps = acc * a[f];
    float pd = acc * a[OUT_F + f];
#pragma unroll
    for (int off = 32; off > 0; off >>= 1) {
        ps += __shfl_xor(ps, off, 64);
        pd += __shfl_xor(pd, off, 64);
    }
    if (f == 0) { s_src[row] = ps; s_dst[row] = pd; }
}

// ---------------------------------------------------------------------------
// K2: out-degree histogram (int atomics), int4 edge loads
// ---------------------------------------------------------------------------
__global__ void __launch_bounds__(256)
gat_degree(const int4* __restrict__ esrc4, int* __restrict__ deg) {
    int i = blockIdx.x * 256 + threadIdx.x;
    if (i < E_EDGES / 4) {
        int4 v = esrc4[i];
        atomicAdd(&deg[v.x], 1);
        atomicAdd(&deg[v.y], 1);
        atomicAdd(&deg[v.z], 1);
        atomicAdd(&deg[v.w], 1);
    }
}

// ---------------------------------------------------------------------------
// K3a/b/c: exclusive prefix sum over deg -> rowptr (and cnt = rowptr copy)
// ---------------------------------------------------------------------------
__global__ void __launch_bounds__(256)
scan_block_reduce(const int* __restrict__ deg, int* __restrict__ bsum) {
    int i = blockIdx.x * 256 + threadIdx.x;
    int v = (i < N_NODES) ? deg[i] : 0;
#pragma unroll
    for (int off = 32; off > 0; off >>= 1) v += __shfl_xor(v, off, 64);
    __shared__ int s[4];
    if ((threadIdx.x & 63) == 0) s[threadIdx.x >> 6] = v;
    __syncthreads();
    if (threadIdx.x == 0) bsum[blockIdx.x] = s[0] + s[1] + s[2] + s[3];
}

__global__ void __launch_bounds__(256)
scan_top(const int* __restrict__ bsum, int* __restrict__ boff) {
    __shared__ int s[256];
    int t = threadIdx.x;
    int v = (t < NB_SCAN) ? bsum[t] : 0;
    s[t] = v;
    __syncthreads();
    for (int d = 1; d < 256; d <<= 1) {
        int add = (t >= d) ? s[t - d] : 0;
        __syncthreads();
        s[t] += add;
        __syncthreads();
    }
    if (t < NB_SCAN) boff[t] = s[t] - v;          // exclusive
}

__global__ void __launch_bounds__(256)
scan_apply(const int* __restrict__ deg, const int* __restrict__ boff,
           int* __restrict__ rowptr, int* __restrict__ cnt) {
    int t = threadIdx.x;
    int i = blockIdx.x * 256 + t;
    __shared__ int s[256];
    int v = (i < N_NODES) ? deg[i] : 0;
    s[t] = v;
    __syncthreads();
    for (int d = 1; d < 256; d <<= 1) {
        int add = (t >= d) ? s[t - d] : 0;
        __syncthreads();
        s[t] += add;
        __syncthreads();
    }
    if (i < N_NODES) {
        int rp = boff[blockIdx.x] + s[t] - v;     // exclusive
        rowptr[i] = rp;
        cnt[i]    = rp;                           // scatter cursor starts at row base
    }
    if (i == 0) rowptr[N_NODES] = E_EDGES;
}

// ---------------------------------------------------------------------------
// K4: per-edge attention weight + bucket into CSR slot.
// Single packed 8B record {dst, ee} per edge -> one scattered line, not two.
// ---------------------------------------------------------------------------
__global__ void __launch_bounds__(256)
gat_edge_scatter(const int* __restrict__ esrc, const int* __restrict__ edst,
                 const float* __restrict__ s_src, const float* __restrict__ s_dst,
                 int* __restrict__ cnt, int2* __restrict__ recs) {
    int e = blockIdx.x * 256 + threadIdx.x;
    if (e >= E_EDGES) return;
    int s = esrc[e];
    int d = edst[e];
    float sc = s_src[s] + s_dst[d];
    float lr = sc > 0.f ? sc : ALPHA * sc;
    float ee = __expf(-lr);
    int pos = atomicAdd(&cnt[s], 1);              // cnt pre-seeded with rowptr
    int2 rec;
    rec.x = d;
    rec.y = __float_as_int(ee);
    recs[pos] = rec;
}

// ---------------------------------------------------------------------------
// K5: per-node segment reduction. One wave per node, lane = feature.
// 4x unrolled so 4 independent h-gathers are in flight per wave.
// Finalize (divide + elu) fused; writes out exactly once -> no out memset.
// ---------------------------------------------------------------------------
__global__ void __launch_bounds__(256)
gat_aggregate(const int* __restrict__ rowptr, const int2* __restrict__ recs,
              const __hip_bfloat16* __restrict__ hb, float* __restrict__ out) {
    int node = blockIdx.x * 4 + (threadIdx.x >> 6);   // 12500 blocks
    int f = threadIdx.x & 63;
    int beg = rowptr[node];
    int end = rowptr[node + 1];
    float acc = 0.f, rs = 0.f;
    int j = beg;
    for (; j + 3 < end; j += 4) {
        int2 r0 = recs[j],     r1 = recs[j + 1];
        int2 r2 = recs[j + 2], r3 = recs[j + 3];
        float e0 = __int_as_float(r0.y), e1 = __int_as_float(r1.y);
        float e2 = __int_as_float(r2.y), e3 = __int_as_float(r3.y);
        float h0 = (float)hb[(size_t)r0.x * OUT_F + f];
        float h1 = (float)hb[(size_t)r1.x * OUT_F + f];
        float h2 = (float)hb[(size_t)r2.x * OUT_F + f];
        float h3 = (float)hb[(size_t)r3.x * OUT_F + f];
        acc += e0 * h0 + e1 * h1 + e2 * h2 + e3 * h3;
        rs  += e0 + e1 + e2 + e3;
    }
    for (; j < end; ++j) {
        int2 r = recs[j];
        float ee = __int_as_float(r.y);
        acc += ee * (float)hb[(size_t)r.x * OUT_F + f];
        rs  += ee;
    }
    float v = (rs != 0.f) ? acc / rs : 0.f;
    out[(size_t)node * OUT_F + f] = v > 0.f ? v : (__expf(v) - 1.f);
}

// ---------------------------------------------------------------------------
extern "C" void kernel_launch(void* const* d_in, const int* in_sizes, int n_in,
                              void* d_out, int out_size, void* d_ws, size_t ws_size,
                              hipStream_t stream) {
    const float* x    = (const float*)d_in[0];
    const int*   edge = (const int*)d_in[1];   // (2, E) int32 row-major
    const float* W    = (const float*)d_in[2];
    const float* a    = (const float*)d_in[3];
    float*       out  = (float*)d_out;

    const int* esrc = edge;
    const int* edst = edge + E_EDGES;

    char* ws = (char*)d_ws;
    size_t off = 0;
    __hip_bfloat16* hb = (__hip_bfloat16*)(ws + off); off += (size_t)N_NODES * OUT_F * 2; // 6.4MB
    float* s_src  = (float*)(ws + off); off += (size_t)N_NODES * 4;
    float* s_dst  = (float*)(ws + off); off += (size_t)N_NODES * 4;
    int*   deg    = (int*)  (ws + off); off += (size_t)N_NODES * 4;
    int*   cnt    = (int*)  (ws + off); off += (size_t)N_NODES * 4;
    int*   rowptr = (int*)  (ws + off); off += (size_t)(N_NODES + 2) * 4;
    int*   bsum   = (int*)  (ws + off); off += 256 * 4;
    int*   boff   = (int*)  (ws + off); off += 256 * 4;
    int2*  recs   = (int2*) (ws + off); off += (size_t)E_EDGES * 8;       // 12.8MB

    hipMemsetAsync(deg, 0, (size_t)N_NODES * 4, stream);

    gat_gemm_scores<<<N_NODES / 4, 256, 0, stream>>>(x, W, a, hb, s_src, s_dst);

    gat_degree<<<(E_EDGES / 4 + 255) / 256, 256, 0, stream>>>((const int4*)esrc, deg);

    scan_block_reduce<<<NB_SCAN, 256, 0, stream>>>(deg, bsum);
    scan_top<<<1, 256, 0, stream>>>(bsum, boff);
    scan_apply<<<NB_SCAN, 256, 0, stream>>>(deg, boff, rowptr, cnt);

    gat_edge_scatter<<<E_EDGES / 256, 256, 0, stream>>>(esrc, edst, s_src, s_dst,
                                                        cnt, recs);

    gat_aggregate<<<N_NODES / 4, 256, 0, stream>>>(rowptr, recs, hb, out);
}

// Round 4
// 255.875 us; speedup vs baseline: 2.1636x; 1.1645x over previous
//
#include <hip/hip_runtime.h>
#include <hip/hip_bf16.h>

#define N_NODES 50000
#define E_EDGES 1600000
#define IN_F    128
#define OUT_F   64
#define ALPHA   0.2f
#define NB_SCAN 196          // ceil(50000/256)
#define BKT_SHIFT 7
#define BKT_NODES 128
#define NBKT 391             // ceil(50000/128)

typedef __bf16 bf16x8 __attribute__((ext_vector_type(8)));
typedef float  f32x4  __attribute__((ext_vector_type(4)));

// ---------------------------------------------------------------------------
// K1: h = X @ W via MFMA 16x16x32 bf16. One wave per 16 rows x 64 cols.
// W fragments loaded once per wave (16x less L1 traffic than per-row scheme).
// Fused epilogue computes s_src/s_dst from the fp32 accumulator.
// A-frag: lane holds A[lane&15][(lane>>4)*8 + j]; B-frag: B[(lane>>4)*8+j][lane&15].
// C/D: col = lane&15, row = (lane>>4)*4 + reg   [m89-verified layout]
// ---------------------------------------------------------------------------
__global__ void __launch_bounds__(256)
gat_gemm_mfma(const float* __restrict__ x, const float* __restrict__ W,
              const float* __restrict__ a,
              __hip_bfloat16* __restrict__ hb,
              float* __restrict__ s_src, float* __restrict__ s_dst) {
    int wave = threadIdx.x >> 6;
    int lane = threadIdx.x & 63;
    int r0 = blockIdx.x * 64 + wave * 16;         // 782 blocks; tail exact
    if (r0 >= N_NODES) return;                    // 50000 = 781*64 + 16

    int col = lane & 15;
    int klo = (lane >> 4) * 8;

    // B fragments: bw[t][s], t = n-tile (cols 16t..16t+15), s = k-step
    bf16x8 bw[4][4];
#pragma unroll
    for (int t = 0; t < 4; ++t)
#pragma unroll
        for (int s = 0; s < 4; ++s)
#pragma unroll
            for (int j = 0; j < 8; ++j)
                bw[t][s][j] = (__bf16)W[(32 * s + klo + j) * OUT_F + 16 * t + col];

    // A fragments: 16 rows, k-steps
    const float* xr = x + ((size_t)(r0 + col)) * IN_F;
    bf16x8 aw[4];
#pragma unroll
    for (int s = 0; s < 4; ++s) {
        float4 v0 = *(const float4*)(xr + 32 * s + klo);
        float4 v1 = *(const float4*)(xr + 32 * s + klo + 4);
        aw[s][0] = (__bf16)v0.x; aw[s][1] = (__bf16)v0.y;
        aw[s][2] = (__bf16)v0.z; aw[s][3] = (__bf16)v0.w;
        aw[s][4] = (__bf16)v1.x; aw[s][5] = (__bf16)v1.y;
        aw[s][6] = (__bf16)v1.z; aw[s][7] = (__bf16)v1.w;
    }

    f32x4 acc0 = {0.f,0.f,0.f,0.f}, acc1 = {0.f,0.f,0.f,0.f};
    f32x4 acc2 = {0.f,0.f,0.f,0.f}, acc3 = {0.f,0.f,0.f,0.f};
#pragma unroll
    for (int s = 0; s < 4; ++s) {
        acc0 = __builtin_amdgcn_mfma_f32_16x16x32_bf16(aw[s], bw[0][s], acc0, 0, 0, 0);
        acc1 = __builtin_amdgcn_mfma_f32_16x16x32_bf16(aw[s], bw[1][s], acc1, 0, 0, 0);
        acc2 = __builtin_amdgcn_mfma_f32_16x16x32_bf16(aw[s], bw[2][s], acc2, 0, 0, 0);
        acc3 = __builtin_amdgcn_mfma_f32_16x16x32_bf16(aw[s], bw[3][s], acc3, 0, 0, 0);
    }

    // Store h (bf16). Lane's rows: grp*4+reg, grp = lane>>4; cols 16t+col.
    int grp = lane >> 4;
#pragma unroll
    for (int reg = 0; reg < 4; ++reg) {
        size_t base = (size_t)(r0 + grp * 4 + reg) * OUT_F + col;
        hb[base +  0] = __float2bfloat16(acc0[reg]);
        hb[base + 16] = __float2bfloat16(acc1[reg]);
        hb[base + 32] = __float2bfloat16(acc2[reg]);
        hb[base + 48] = __float2bfloat16(acc3[reg]);
    }

    // Scores: per-row dot of h with a_src / a_dst; reduce over lane&15.
    float as0 = a[col], as1 = a[16 + col], as2 = a[32 + col], as3 = a[48 + col];
    float ad0 = a[64 + col], ad1 = a[80 + col], ad2 = a[96 + col], ad3 = a[112 + col];
#pragma unroll
    for (int reg = 0; reg < 4; ++reg) {
        float ps = acc0[reg] * as0 + acc1[reg] * as1 + acc2[reg] * as2 + acc3[reg] * as3;
        float pd = acc0[reg] * ad0 + acc1[reg] * ad1 + acc2[reg] * ad2 + acc3[reg] * ad3;
#pragma unroll
        for (int off = 1; off < 16; off <<= 1) {
            ps += __shfl_xor(ps, off, 64);
            pd += __shfl_xor(pd, off, 64);
        }
        if (col == 0) {
            s_src[r0 + grp * 4 + reg] = ps;
            s_dst[r0 + grp * 4 + reg] = pd;
        }
    }
}

// ---------------------------------------------------------------------------
// K2: out-degree histogram (int atomics), int4 edge loads
// ---------------------------------------------------------------------------
__global__ void __launch_bounds__(256)
gat_degree(const int4* __restrict__ esrc4, int* __restrict__ deg) {
    int i = blockIdx.x * 256 + threadIdx.x;
    if (i < E_EDGES / 4) {
        int4 v = esrc4[i];
        atomicAdd(&deg[v.x], 1);
        atomicAdd(&deg[v.y], 1);
        atomicAdd(&deg[v.z], 1);
        atomicAdd(&deg[v.w], 1);
    }
}

// ---------------------------------------------------------------------------
// K3: exclusive prefix sum over deg -> rowptr; also seeds bucket cursors
// ---------------------------------------------------------------------------
__global__ void __launch_bounds__(256)
scan_block_reduce(const int* __restrict__ deg, int* __restrict__ bsum) {
    int i = blockIdx.x * 256 + threadIdx.x;
    int v = (i < N_NODES) ? deg[i] : 0;
#pragma unroll
    for (int off = 32; off > 0; off >>= 1) v += __shfl_xor(v, off, 64);
    __shared__ int s[4];
    if ((threadIdx.x & 63) == 0) s[threadIdx.x >> 6] = v;
    __syncthreads();
    if (threadIdx.x == 0) bsum[blockIdx.x] = s[0] + s[1] + s[2] + s[3];
}

__global__ void __launch_bounds__(256)
scan_top(const int* __restrict__ bsum, int* __restrict__ boff) {
    __shared__ int s[256];
    int t = threadIdx.x;
    int v = (t < NB_SCAN) ? bsum[t] : 0;
    s[t] = v;
    __syncthreads();
    for (int d = 1; d < 256; d <<= 1) {
        int add = (t >= d) ? s[t - d] : 0;
        __syncthreads();
        s[t] += add;
        __syncthreads();
    }
    if (t < NB_SCAN) boff[t] = s[t] - v;          // exclusive
}

__global__ void __launch_bounds__(256)
scan_apply(const int* __restrict__ deg, const int* __restrict__ boff,
           int* __restrict__ rowptr, int* __restrict__ bcur_pad) {
    int t = threadIdx.x;
    int i = blockIdx.x * 256 + t;
    __shared__ int s[256];
    int v = (i < N_NODES) ? deg[i] : 0;
    s[t] = v;
    __syncthreads();
    for (int d = 1; d < 256; d <<= 1) {
        int add = (t >= d) ? s[t - d] : 0;
        __syncthreads();
        s[t] += add;
        __syncthreads();
    }
    if (i < N_NODES) {
        int rp = boff[blockIdx.x] + s[t] - v;     // exclusive
        rowptr[i] = rp;
        if ((i & (BKT_NODES - 1)) == 0)
            bcur_pad[(i >> BKT_SHIFT) * 16] = rp; // 64B-padded cursor
    }
    if (i == 0) rowptr[N_NODES] = E_EDGES;
}

// ---------------------------------------------------------------------------
// K4a: pass 1 — append {src:dst packed, ee} to coarse bucket (128 nodes each).
// Appending writes advance 391 cursors sequentially -> cache lines fill.
// ---------------------------------------------------------------------------
__global__ void __launch_bounds__(256)
gat_edge_pass1(const int* __restrict__ esrc, const int* __restrict__ edst,
               const float* __restrict__ s_src, const float* __restrict__ s_dst,
               int* __restrict__ bcur_pad, int2* __restrict__ recs_tmp) {
    int e = blockIdx.x * 256 + threadIdx.x;
    if (e >= E_EDGES) return;
    int s = esrc[e];
    int d = edst[e];
    float sc = s_src[s] + s_dst[d];
    float lr = sc > 0.f ? sc : ALPHA * sc;
    float ee = __expf(-lr);
    int pos = atomicAdd(&bcur_pad[(s >> BKT_SHIFT) * 16], 1);
    recs_tmp[pos] = make_int2((s << 16) | d, __float_as_int(ee));  // s,d < 2^16
}

// ---------------------------------------------------------------------------
// K4b: pass 2 — one block per bucket; LDS cursors seeded from rowptr;
// scatter within the bucket's ~33KB window (L2-resident -> lines fill).
// ---------------------------------------------------------------------------
__global__ void __launch_bounds__(256)
gat_edge_pass2(const int* __restrict__ rowptr, const int2* __restrict__ recs_tmp,
               int2* __restrict__ recs) {
    int b = blockIdx.x;                            // NBKT blocks
    int t = threadIdx.x;
    __shared__ int lcnt[BKT_NODES];
    int nbase = b << BKT_SHIFT;
    if (t < BKT_NODES) {
        int node = nbase + t;
        lcnt[t] = (node < N_NODES) ? rowptr[node] : 0;
    }
    __syncthreads();
    int beg = rowptr[nbase];
    int endn = nbase + BKT_NODES;
    int end = rowptr[endn > N_NODES ? N_NODES : endn];
    for (int j = beg + t; j < end; j += 256) {
        int2 r = recs_tmp[j];
        int s = ((unsigned)r.x) >> 16;
        int d = r.x & 0xFFFF;
        int pos = atomicAdd(&lcnt[s & (BKT_NODES - 1)], 1);
        recs[pos] = make_int2(d, r.y);
    }
}

// ---------------------------------------------------------------------------
// K5: per-node segment reduction. One wave per node, lane = feature.
// ---------------------------------------------------------------------------
__global__ void __launch_bounds__(256)
gat_aggregate(const int* __restrict__ rowptr, const int2* __restrict__ recs,
              const __hip_bfloat16* __restrict__ hb, float* __restrict__ out) {
    int node = blockIdx.x * 4 + (threadIdx.x >> 6);   // 12500 blocks
    int f = threadIdx.x & 63;
    int beg = rowptr[node];
    int end = rowptr[node + 1];
    float acc = 0.f, rs = 0.f;
    int j = beg;
    for (; j + 3 < end; j += 4) {
        int2 r0 = recs[j],     r1 = recs[j + 1];
        int2 r2 = recs[j + 2], r3 = recs[j + 3];
        float e0 = __int_as_float(r0.y), e1 = __int_as_float(r1.y);
        float e2 = __int_as_float(r2.y), e3 = __int_as_float(r3.y);
        float h0 = (float)hb[(size_t)r0.x * OUT_F + f];
        float h1 = (float)hb[(size_t)r1.x * OUT_F + f];
        float h2 = (float)hb[(size_t)r2.x * OUT_F + f];
        float h3 = (float)hb[(size_t)r3.x * OUT_F + f];
        acc += e0 * h0 + e1 * h1 + e2 * h2 + e3 * h3;
        rs  += e0 + e1 + e2 + e3;
    }
    for (; j < end; ++j) {
        int2 r = recs[j];
        float ee = __int_as_float(r.y);
        acc += ee * (float)hb[(size_t)r.x * OUT_F + f];
        rs  += ee;
    }
    float v = (rs != 0.f) ? acc / rs : 0.f;
    out[(size_t)node * OUT_F + f] = v > 0.f ? v : (__expf(v) - 1.f);
}

// ---------------------------------------------------------------------------
extern "C" void kernel_launch(void* const* d_in, const int* in_sizes, int n_in,
                              void* d_out, int out_size, void* d_ws, size_t ws_size,
                              hipStream_t stream) {
    const float* x    = (const float*)d_in[0];
    const int*   edge = (const int*)d_in[1];   // (2, E) int32 row-major
    const float* W    = (const float*)d_in[2];
    const float* a    = (const float*)d_in[3];
    float*       out  = (float*)d_out;

    const int* esrc = edge;
    const int* edst = edge + E_EDGES;

    char* ws = (char*)d_ws;
    size_t off = 0;
    __hip_bfloat16* hb = (__hip_bfloat16*)(ws + off); off += (size_t)N_NODES * OUT_F * 2; // 6.4MB
    float* s_src  = (float*)(ws + off); off += (size_t)N_NODES * 4;
    float* s_dst  = (float*)(ws + off); off += (size_t)N_NODES * 4;
    int*   deg    = (int*)  (ws + off); off += (size_t)N_NODES * 4;
    int*   rowptr = (int*)  (ws + off); off += (size_t)(N_NODES + 2) * 4;
    int*   bsum   = (int*)  (ws + off); off += 256 * 4;
    int*   boff   = (int*)  (ws + off); off += 256 * 4;
    int*   bcur   = (int*)  (ws + off); off += (size_t)NBKT * 16 * 4;     // 64B-padded
    int2*  recs_tmp = (int2*)(ws + off); off += (size_t)E_EDGES * 8;      // 12.8MB
    int2*  recs     = (int2*)(ws + off); off += (size_t)E_EDGES * 8;      // 12.8MB

    hipMemsetAsync(deg, 0, (size_t)N_NODES * 4, stream);

    gat_gemm_mfma<<<(N_NODES + 63) / 64, 256, 0, stream>>>(x, W, a, hb, s_src, s_dst);

    gat_degree<<<(E_EDGES / 4 + 255) / 256, 256, 0, stream>>>((const int4*)esrc, deg);

    scan_block_reduce<<<NB_SCAN, 256, 0, stream>>>(deg, bsum);
    scan_top<<<1, 256, 0, stream>>>(bsum, boff);
    scan_apply<<<NB_SCAN, 256, 0, stream>>>(deg, boff, rowptr, bcur);

    gat_edge_pass1<<<E_EDGES / 256, 256, 0, stream>>>(esrc, edst, s_src, s_dst,
                                                      bcur, recs_tmp);

    gat_edge_pass2<<<NBKT, 256, 0, stream>>>(rowptr, recs_tmp, recs);

    gat_aggregate<<<N_NODES / 4, 256, 0, stream>>>(rowptr, recs, hb, out);
}

// Round 5
// 126.335 us; speedup vs baseline: 4.3820x; 2.0254x over previous
//
#include <hip/hip_runtime.h>
#include <hip/hip_bf16.h>

#define N_NODES 50000
#define E_EDGES 1600000
#define IN_F    128
#define OUT_F   64
#define ALPHA   0.2f

#define BKT_SHIFT 8
#define BKT_NODES 256
#define NBKT 196                 // ceil(50000/256)
#define BKT_CAP 16384            // per-bucket record capacity (mean 8192, 90 sigma)
#define CHUNK 4096               // edges per binning block
#define NBLK_BIN 391             // ceil(1600000/4096)

typedef __bf16 bf16x8 __attribute__((ext_vector_type(8)));
typedef float  f32x4  __attribute__((ext_vector_type(4)));

// ---------------------------------------------------------------------------
// K1: h = X @ W via MFMA 16x16x32 bf16. One wave per 16 rows x 64 cols.
// Fused epilogue computes s_src/s_dst from the fp32 accumulator.
// C/D layout: col = lane&15, row = (lane>>4)*4 + reg   [m89-verified]
// ---------------------------------------------------------------------------
__global__ void __launch_bounds__(256)
gat_gemm_mfma(const float* __restrict__ x, const float* __restrict__ W,
              const float* __restrict__ a,
              __hip_bfloat16* __restrict__ hb,
              float* __restrict__ s_src, float* __restrict__ s_dst) {
    int wave = threadIdx.x >> 6;
    int lane = threadIdx.x & 63;
    int r0 = blockIdx.x * 64 + wave * 16;
    if (r0 >= N_NODES) return;                    // 50000 = 781*64 + 16

    int col = lane & 15;
    int klo = (lane >> 4) * 8;

    bf16x8 bw[4][4];
#pragma unroll
    for (int t = 0; t < 4; ++t)
#pragma unroll
        for (int s = 0; s < 4; ++s)
#pragma unroll
            for (int j = 0; j < 8; ++j)
                bw[t][s][j] = (__bf16)W[(32 * s + klo + j) * OUT_F + 16 * t + col];

    const float* xr = x + ((size_t)(r0 + col)) * IN_F;
    bf16x8 aw[4];
#pragma unroll
    for (int s = 0; s < 4; ++s) {
        float4 v0 = *(const float4*)(xr + 32 * s + klo);
        float4 v1 = *(const float4*)(xr + 32 * s + klo + 4);
        aw[s][0] = (__bf16)v0.x; aw[s][1] = (__bf16)v0.y;
        aw[s][2] = (__bf16)v0.z; aw[s][3] = (__bf16)v0.w;
        aw[s][4] = (__bf16)v1.x; aw[s][5] = (__bf16)v1.y;
        aw[s][6] = (__bf16)v1.z; aw[s][7] = (__bf16)v1.w;
    }

    f32x4 acc0 = {0.f,0.f,0.f,0.f}, acc1 = {0.f,0.f,0.f,0.f};
    f32x4 acc2 = {0.f,0.f,0.f,0.f}, acc3 = {0.f,0.f,0.f,0.f};
#pragma unroll
    for (int s = 0; s < 4; ++s) {
        acc0 = __builtin_amdgcn_mfma_f32_16x16x32_bf16(aw[s], bw[0][s], acc0, 0, 0, 0);
        acc1 = __builtin_amdgcn_mfma_f32_16x16x32_bf16(aw[s], bw[1][s], acc1, 0, 0, 0);
        acc2 = __builtin_amdgcn_mfma_f32_16x16x32_bf16(aw[s], bw[2][s], acc2, 0, 0, 0);
        acc3 = __builtin_amdgcn_mfma_f32_16x16x32_bf16(aw[s], bw[3][s], acc3, 0, 0, 0);
    }

    int grp = lane >> 4;
#pragma unroll
    for (int reg = 0; reg < 4; ++reg) {
        size_t base = (size_t)(r0 + grp * 4 + reg) * OUT_F + col;
        hb[base +  0] = __float2bfloat16(acc0[reg]);
        hb[base + 16] = __float2bfloat16(acc1[reg]);
        hb[base + 32] = __float2bfloat16(acc2[reg]);
        hb[base + 48] = __float2bfloat16(acc3[reg]);
    }

    float as0 = a[col], as1 = a[16 + col], as2 = a[32 + col], as3 = a[48 + col];
    float ad0 = a[64 + col], ad1 = a[80 + col], ad2 = a[96 + col], ad3 = a[112 + col];
#pragma unroll
    for (int reg = 0; reg < 4; ++reg) {
        float ps = acc0[reg] * as0 + acc1[reg] * as1 + acc2[reg] * as2 + acc3[reg] * as3;
        float pd = acc0[reg] * ad0 + acc1[reg] * ad1 + acc2[reg] * ad2 + acc3[reg] * ad3;
#pragma unroll
        for (int off = 1; off < 16; off <<= 1) {
            ps += __shfl_xor(ps, off, 64);
            pd += __shfl_xor(pd, off, 64);
        }
        if (col == 0) {
            s_src[r0 + grp * 4 + reg] = ps;
            s_dst[r0 + grp * 4 + reg] = pd;
        }
    }
}

// ---------------------------------------------------------------------------
// K0: seed bucket cursors at fixed-stride region bases
// ---------------------------------------------------------------------------
__global__ void __launch_bounds__(256)
gat_init_cursors(int* __restrict__ bcur) {
    int t = threadIdx.x;
    if (t < NBKT) bcur[t] = t * BKT_CAP;
}

// ---------------------------------------------------------------------------
// K2: LDS counting-sort binning. Each block bins CHUNK edges by bucket
// (= src>>8) in LDS, reserves global space with ONE atomic per bucket,
// flushes contiguous runs -> full-line writes. Records are 4B (src<<16|dst).
// ---------------------------------------------------------------------------
__global__ void __launch_bounds__(256)
gat_bin(const int* __restrict__ esrc, const int* __restrict__ edst,
        int* __restrict__ bcur, unsigned* __restrict__ recs_tmp) {
    __shared__ unsigned recs_l[CHUNK];     // 16KB
    __shared__ int cnt[NBKT];
    __shared__ int start[256];
    __shared__ int gbase[NBKT];
    __shared__ int sc[256];

    int t = threadIdx.x;
    int ebase = blockIdx.x * CHUNK;

    if (t < NBKT) cnt[t] = 0;
    __syncthreads();

    unsigned rec[16];
    int      loc[16];
#pragma unroll
    for (int k = 0; k < 16; ++k) {
        int e = ebase + k * 256 + t;
        if (e < E_EDGES) {
            unsigned s = (unsigned)esrc[e];
            unsigned d = (unsigned)edst[e];
            rec[k] = (s << 16) | d;
            loc[k] = atomicAdd(&cnt[s >> BKT_SHIFT], 1);
        } else {
            loc[k] = -1;
            rec[k] = 0;
        }
    }
    __syncthreads();

    // exclusive scan of cnt -> start (Hillis-Steele over 256)
    int v = (t < NBKT) ? cnt[t] : 0;
    sc[t] = v;
    __syncthreads();
    for (int d = 1; d < 256; d <<= 1) {
        int add = (t >= d) ? sc[t - d] : 0;
        __syncthreads();
        sc[t] += add;
        __syncthreads();
    }
    start[t] = sc[t] - v;
    __syncthreads();

    // place records into LDS, bucket-grouped
#pragma unroll
    for (int k = 0; k < 16; ++k)
        if (loc[k] >= 0)
            recs_l[start[rec[k] >> 24] + loc[k]] = rec[k];

    // reserve global space, one atomic per bucket
    if (t < NBKT) {
        int c = cnt[t];
        gbase[t] = (c > 0) ? atomicAdd(&bcur[t], c) : 0;
    }
    __syncthreads();

    // flush: consecutive LDS slots -> consecutive global slots per bucket
    int total = min(CHUNK, E_EDGES - ebase);
    for (int i = t; i < total; i += 256) {
        unsigned r = recs_l[i];
        int b = r >> 24;
        int pos = gbase[b] + (i - start[b]);
        if (pos < (b + 1) * BKT_CAP)               // 90-sigma guard, never trips
            recs_tmp[pos] = r;
    }
}

// ---------------------------------------------------------------------------
// K3: per-bucket pass: LDS histogram of its 256 nodes -> rowptr/dcnt,
// then compute ee and place {dst, ee} sorted-by-src within the bucket's
// fixed-stride output region (64KB window, L2-resident writes).
// ---------------------------------------------------------------------------
__global__ void __launch_bounds__(256)
gat_pass2(const int* __restrict__ bcur, const unsigned* __restrict__ recs_tmp,
          const float* __restrict__ s_src, const float* __restrict__ s_dst,
          int* __restrict__ rowptr, int* __restrict__ dcnt,
          int2* __restrict__ recs) {
    __shared__ int ncnt[256];
    __shared__ int lcur[256];
    __shared__ int sc[256];

    int b = blockIdx.x;
    int t = threadIdx.x;
    int nbase = b << BKT_SHIFT;
    int rbase = b * BKT_CAP;
    int m = bcur[b] - rbase;                       // records in this bucket

    ncnt[t] = 0;
    __syncthreads();

    for (int i = t; i < m; i += 256) {
        unsigned r = recs_tmp[rbase + i];
        atomicAdd(&ncnt[(r >> 16) & (BKT_NODES - 1)], 1);
    }
    __syncthreads();

    // exclusive scan ncnt -> per-node start within bucket
    int v = ncnt[t];
    sc[t] = v;
    __syncthreads();
    for (int d = 1; d < 256; d <<= 1) {
        int add = (t >= d) ? sc[t - d] : 0;
        __syncthreads();
        sc[t] += add;
        __syncthreads();
    }
    int nstart = sc[t] - v;
    lcur[t] = nstart;
    int node = nbase + t;
    if (node < N_NODES) {
        rowptr[node] = rbase + nstart;             // positions in strided recs
        dcnt[node]   = v;
    }
    __syncthreads();

    for (int i = t; i < m; i += 256) {
        unsigned r = recs_tmp[rbase + i];
        int s = r >> 16;
        int d = r & 0xFFFF;
        float sco = s_src[s] + s_dst[d];
        float lr = sco > 0.f ? sco : ALPHA * sco;
        float ee = __expf(-lr);
        int idx = atomicAdd(&lcur[s & (BKT_NODES - 1)], 1);
        recs[rbase + idx] = make_int2(d, __float_as_int(ee));
    }
}

// ---------------------------------------------------------------------------
// K4: per-node segment reduction. One wave per node, lane = feature.
// ---------------------------------------------------------------------------
__global__ void __launch_bounds__(256)
gat_aggregate(const int* __restrict__ rowptr, const int* __restrict__ dcnt,
              const int2* __restrict__ recs,
              const __hip_bfloat16* __restrict__ hb, float* __restrict__ out) {
    int node = blockIdx.x * 4 + (threadIdx.x >> 6);   // 12500 blocks
    int f = threadIdx.x & 63;
    int beg = rowptr[node];
    int end = beg + dcnt[node];
    float acc = 0.f, rs = 0.f;
    int j = beg;
    for (; j + 3 < end; j += 4) {
        int2 r0 = recs[j],     r1 = recs[j + 1];
        int2 r2 = recs[j + 2], r3 = recs[j + 3];
        float e0 = __int_as_float(r0.y), e1 = __int_as_float(r1.y);
        float e2 = __int_as_float(r2.y), e3 = __int_as_float(r3.y);
        float h0 = (float)hb[(size_t)r0.x * OUT_F + f];
        float h1 = (float)hb[(size_t)r1.x * OUT_F + f];
        float h2 = (float)hb[(size_t)r2.x * OUT_F + f];
        float h3 = (float)hb[(size_t)r3.x * OUT_F + f];
        acc += e0 * h0 + e1 * h1 + e2 * h2 + e3 * h3;
        rs  += e0 + e1 + e2 + e3;
    }
    for (; j < end; ++j) {
        int2 r = recs[j];
        float ee = __int_as_float(r.y);
        acc += ee * (float)hb[(size_t)r.x * OUT_F + f];
        rs  += ee;
    }
    float v = (rs != 0.f) ? acc / rs : 0.f;
    out[(size_t)node * OUT_F + f] = v > 0.f ? v : (__expf(v) - 1.f);
}

// ---------------------------------------------------------------------------
extern "C" void kernel_launch(void* const* d_in, const int* in_sizes, int n_in,
                              void* d_out, int out_size, void* d_ws, size_t ws_size,
                              hipStream_t stream) {
    const float* x    = (const float*)d_in[0];
    const int*   edge = (const int*)d_in[1];   // (2, E) int32 row-major
    const float* W    = (const float*)d_in[2];
    const float* a    = (const float*)d_in[3];
    float*       out  = (float*)d_out;

    const int* esrc = edge;
    const int* edst = edge + E_EDGES;

    char* ws = (char*)d_ws;
    size_t off = 0;
    __hip_bfloat16* hb = (__hip_bfloat16*)(ws + off); off += (size_t)N_NODES * OUT_F * 2; // 6.4MB
    float* s_src  = (float*)(ws + off); off += (size_t)N_NODES * 4;
    float* s_dst  = (float*)(ws + off); off += (size_t)N_NODES * 4;
    int*   rowptr = (int*)  (ws + off); off += (size_t)N_NODES * 4;
    int*   dcnt   = (int*)  (ws + off); off += (size_t)N_NODES * 4;
    int*   bcur   = (int*)  (ws + off); off += 256 * 4;
    unsigned* recs_tmp = (unsigned*)(ws + off); off += (size_t)NBKT * BKT_CAP * 4;  // 12.8MB
    int2*     recs     = (int2*)    (ws + off); off += (size_t)NBKT * BKT_CAP * 8;  // 25.6MB

    gat_init_cursors<<<1, 256, 0, stream>>>(bcur);

    gat_gemm_mfma<<<(N_NODES + 63) / 64, 256, 0, stream>>>(x, W, a, hb, s_src, s_dst);

    gat_bin<<<NBLK_BIN, 256, 0, stream>>>(esrc, edst, bcur, recs_tmp);

    gat_pass2<<<NBKT, 256, 0, stream>>>(bcur, recs_tmp, s_src, s_dst,
                                        rowptr, dcnt, recs);

    gat_aggregate<<<N_NODES / 4, 256, 0, stream>>>(rowptr, dcnt, recs, hb, out);
}

// Round 6
// 126.301 us; speedup vs baseline: 4.3832x; 1.0003x over previous
//
#include <hip/hip_runtime.h>
#include <hip/hip_bf16.h>

#define N_NODES 50000
#define E_EDGES 1600000
#define IN_F    128
#define OUT_F   64
#define ALPHA   0.2f

#define BKT_SHIFT 8
#define BKT_NODES 256
#define NBKT 196                 // ceil(50000/256)
#define BKT_CAP 16384            // per-bucket record capacity (mean 8192, 90 sigma)
#define CHUNK 4096               // edges per binning block
#define NBLK_BIN 391             // ceil(1600000/4096)

typedef __bf16 bf16x8 __attribute__((ext_vector_type(8)));
typedef float  f32x4  __attribute__((ext_vector_type(4)));

// ---------------------------------------------------------------------------
// K1: h = X @ W via MFMA 16x16x32 bf16. One wave per 16 rows x 64 cols.
// Fused epilogue computes s_src/s_dst from the fp32 accumulator.
// C/D layout: col = lane&15, row = (lane>>4)*4 + reg   [m89-verified]
// ---------------------------------------------------------------------------
__global__ void __launch_bounds__(256)
gat_gemm_mfma(const float* __restrict__ x, const float* __restrict__ W,
              const float* __restrict__ a,
              __hip_bfloat16* __restrict__ hb,
              float* __restrict__ s_src, float* __restrict__ s_dst) {
    int wave = threadIdx.x >> 6;
    int lane = threadIdx.x & 63;
    int r0 = blockIdx.x * 64 + wave * 16;
    if (r0 >= N_NODES) return;                    // 50000 = 781*64 + 16

    int col = lane & 15;
    int klo = (lane >> 4) * 8;

    bf16x8 bw[4][4];
#pragma unroll
    for (int t = 0; t < 4; ++t)
#pragma unroll
        for (int s = 0; s < 4; ++s)
#pragma unroll
            for (int j = 0; j < 8; ++j)
                bw[t][s][j] = (__bf16)W[(32 * s + klo + j) * OUT_F + 16 * t + col];

    const float* xr = x + ((size_t)(r0 + col)) * IN_F;
    bf16x8 aw[4];
#pragma unroll
    for (int s = 0; s < 4; ++s) {
        float4 v0 = *(const float4*)(xr + 32 * s + klo);
        float4 v1 = *(const float4*)(xr + 32 * s + klo + 4);
        aw[s][0] = (__bf16)v0.x; aw[s][1] = (__bf16)v0.y;
        aw[s][2] = (__bf16)v0.z; aw[s][3] = (__bf16)v0.w;
        aw[s][4] = (__bf16)v1.x; aw[s][5] = (__bf16)v1.y;
        aw[s][6] = (__bf16)v1.z; aw[s][7] = (__bf16)v1.w;
    }

    f32x4 acc0 = {0.f,0.f,0.f,0.f}, acc1 = {0.f,0.f,0.f,0.f};
    f32x4 acc2 = {0.f,0.f,0.f,0.f}, acc3 = {0.f,0.f,0.f,0.f};
#pragma unroll
    for (int s = 0; s < 4; ++s) {
        acc0 = __builtin_amdgcn_mfma_f32_16x16x32_bf16(aw[s], bw[0][s], acc0, 0, 0, 0);
        acc1 = __builtin_amdgcn_mfma_f32_16x16x32_bf16(aw[s], bw[1][s], acc1, 0, 0, 0);
        acc2 = __builtin_amdgcn_mfma_f32_16x16x32_bf16(aw[s], bw[2][s], acc2, 0, 0, 0);
        acc3 = __builtin_amdgcn_mfma_f32_16x16x32_bf16(aw[s], bw[3][s], acc3, 0, 0, 0);
    }

    int grp = lane >> 4;
#pragma unroll
    for (int reg = 0; reg < 4; ++reg) {
        size_t base = (size_t)(r0 + grp * 4 + reg) * OUT_F + col;
        hb[base +  0] = __float2bfloat16(acc0[reg]);
        hb[base + 16] = __float2bfloat16(acc1[reg]);
        hb[base + 32] = __float2bfloat16(acc2[reg]);
        hb[base + 48] = __float2bfloat16(acc3[reg]);
    }

    float as0 = a[col], as1 = a[16 + col], as2 = a[32 + col], as3 = a[48 + col];
    float ad0 = a[64 + col], ad1 = a[80 + col], ad2 = a[96 + col], ad3 = a[112 + col];
#pragma unroll
    for (int reg = 0; reg < 4; ++reg) {
        float ps = acc0[reg] * as0 + acc1[reg] * as1 + acc2[reg] * as2 + acc3[reg] * as3;
        float pd = acc0[reg] * ad0 + acc1[reg] * ad1 + acc2[reg] * ad2 + acc3[reg] * ad3;
#pragma unroll
        for (int off = 1; off < 16; off <<= 1) {
            ps += __shfl_xor(ps, off, 64);
            pd += __shfl_xor(pd, off, 64);
        }
        if (col == 0) {
            s_src[r0 + grp * 4 + reg] = ps;
            s_dst[r0 + grp * 4 + reg] = pd;
        }
    }
}

// ---------------------------------------------------------------------------
// K0: seed bucket cursors at fixed-stride region bases
// ---------------------------------------------------------------------------
__global__ void __launch_bounds__(256)
gat_init_cursors(int* __restrict__ bcur) {
    int t = threadIdx.x;
    if (t < NBKT) bcur[t] = t * BKT_CAP;
}

// ---------------------------------------------------------------------------
// K2: LDS counting-sort binning. Each block bins CHUNK edges by bucket
// (= src>>8) in LDS, reserves global space with ONE atomic per bucket,
// flushes contiguous runs -> full-line writes. Records are 4B (src<<16|dst).
// ---------------------------------------------------------------------------
__global__ void __launch_bounds__(256)
gat_bin(const int* __restrict__ esrc, const int* __restrict__ edst,
        int* __restrict__ bcur, unsigned* __restrict__ recs_tmp) {
    __shared__ unsigned recs_l[CHUNK];     // 16KB
    __shared__ int cnt[NBKT];
    __shared__ int start[256];
    __shared__ int gbase[NBKT];
    __shared__ int sc[256];

    int t = threadIdx.x;
    int ebase = blockIdx.x * CHUNK;

    if (t < NBKT) cnt[t] = 0;
    __syncthreads();

    unsigned rec[16];
    int      loc[16];
#pragma unroll
    for (int k = 0; k < 16; ++k) {
        int e = ebase + k * 256 + t;
        if (e < E_EDGES) {
            unsigned s = (unsigned)esrc[e];
            unsigned d = (unsigned)edst[e];
            rec[k] = (s << 16) | d;
            loc[k] = atomicAdd(&cnt[s >> BKT_SHIFT], 1);
        } else {
            loc[k] = -1;
            rec[k] = 0;
        }
    }
    __syncthreads();

    // exclusive scan of cnt -> start (Hillis-Steele over 256)
    int v = (t < NBKT) ? cnt[t] : 0;
    sc[t] = v;
    __syncthreads();
    for (int d = 1; d < 256; d <<= 1) {
        int add = (t >= d) ? sc[t - d] : 0;
        __syncthreads();
        sc[t] += add;
        __syncthreads();
    }
    start[t] = sc[t] - v;
    __syncthreads();

    // place records into LDS, bucket-grouped
#pragma unroll
    for (int k = 0; k < 16; ++k)
        if (loc[k] >= 0)
            recs_l[start[rec[k] >> 24] + loc[k]] = rec[k];

    // reserve global space, one atomic per bucket
    if (t < NBKT) {
        int c = cnt[t];
        gbase[t] = (c > 0) ? atomicAdd(&bcur[t], c) : 0;
    }
    __syncthreads();

    // flush: consecutive LDS slots -> consecutive global slots per bucket
    int total = min(CHUNK, E_EDGES - ebase);
    for (int i = t; i < total; i += 256) {
        unsigned r = recs_l[i];
        int b = r >> 24;
        int pos = gbase[b] + (i - start[b]);
        if (pos < (b + 1) * BKT_CAP)               // 90-sigma guard, never trips
            recs_tmp[pos] = r;
    }
}

// ---------------------------------------------------------------------------
// K3: per-bucket pass: LDS histogram of its 256 nodes -> rowptr/dcnt,
// then compute ee and place {dst, ee} sorted-by-src within the bucket's
// fixed-stride output region (64KB window, L2-resident writes).
// ---------------------------------------------------------------------------
__global__ void __launch_bounds__(256)
gat_pass2(const int* __restrict__ bcur, const unsigned* __restrict__ recs_tmp,
          const float* __restrict__ s_src, const float* __restrict__ s_dst,
          int* __restrict__ rowptr, int* __restrict__ dcnt,
          int2* __restrict__ recs) {
    __shared__ int ncnt[256];
    __shared__ int lcur[256];
    __shared__ int sc[256];

    int b = blockIdx.x;
    int t = threadIdx.x;
    int nbase = b << BKT_SHIFT;
    int rbase = b * BKT_CAP;
    int m = bcur[b] - rbase;                       // records in this bucket

    ncnt[t] = 0;
    __syncthreads();

    for (int i = t; i < m; i += 256) {
        unsigned r = recs_tmp[rbase + i];
        atomicAdd(&ncnt[(r >> 16) & (BKT_NODES - 1)], 1);
    }
    __syncthreads();

    // exclusive scan ncnt -> per-node start within bucket
    int v = ncnt[t];
    sc[t] = v;
    __syncthreads();
    for (int d = 1; d < 256; d <<= 1) {
        int add = (t >= d) ? sc[t - d] : 0;
        __syncthreads();
        sc[t] += add;
        __syncthreads();
    }
    int nstart = sc[t] - v;
    lcur[t] = nstart;
    int node = nbase + t;
    if (node < N_NODES) {
        rowptr[node] = rbase + nstart;             // positions in strided recs
        dcnt[node]   = v;
    }
    __syncthreads();

    for (int i = t; i < m; i += 256) {
        unsigned r = recs_tmp[rbase + i];
        int s = r >> 16;
        int d = r & 0xFFFF;
        float sco = s_src[s] + s_dst[d];
        float lr = sco > 0.f ? sco : ALPHA * sco;
        float ee = __expf(-lr);
        int idx = atomicAdd(&lcur[s & (BKT_NODES - 1)], 1);
        recs[rbase + idx] = make_int2(d, __float_as_int(ee));
    }
}

// ---------------------------------------------------------------------------
// K4: per-node segment reduction, half-wave per edge.
// Lanes 0-31 process edge k, lanes 32-63 process edge nh+k (nh uniform).
// Each lane loads a packed bf16 pair (1 dword, 32 lanes = full 128B row),
// bf16->f32 via shifts; halves merged with shfl_xor(32); lanes<32 store float2.
// ---------------------------------------------------------------------------
__global__ void __launch_bounds__(256)
gat_aggregate(const int* __restrict__ rowptr, const int* __restrict__ dcnt,
              const int2* __restrict__ recs,
              const __hip_bfloat16* __restrict__ hb, float* __restrict__ out) {
    int node = blockIdx.x * 4 + (threadIdx.x >> 6);   // 12500 blocks
    int lane = threadIdx.x & 63;
    int half = lane >> 5;            // 0 or 1
    int c    = lane & 31;            // feature-pair index (features 2c, 2c+1)
    int beg = rowptr[node];
    int n   = dcnt[node];
    int nh  = (n + 1) >> 1;          // uniform across wave
    int lim = half ? (n - nh) : nh;  // valid iterations for this half
    const int2* rp = recs + beg + (half ? nh : 0);
    const unsigned* hbu = (const unsigned*)hb;

    float acc0 = 0.f, acc1 = 0.f, rs = 0.f;
#pragma unroll 8
    for (int k = 0; k < nh; ++k) {
        int2 r = (k < lim) ? rp[k] : make_int2(0, 0);   // ee bits 0 -> 0.0f
        float ee = __int_as_float(r.y);
        unsigned u = hbu[(unsigned)r.x * 32 + c];       // 2 bf16 packed
        float h0 = __uint_as_float(u << 16);
        float h1 = __uint_as_float(u & 0xffff0000u);
        acc0 += ee * h0;
        acc1 += ee * h1;
        rs   += ee;
    }
    acc0 += __shfl_xor(acc0, 32, 64);
    acc1 += __shfl_xor(acc1, 32, 64);
    rs   += __shfl_xor(rs, 32, 64);
    if (half == 0) {
        float inv = (rs != 0.f) ? 1.f / rs : 0.f;
        float v0 = acc0 * inv, v1 = acc1 * inv;
        v0 = v0 > 0.f ? v0 : (__expf(v0) - 1.f);
        v1 = v1 > 0.f ? v1 : (__expf(v1) - 1.f);
        *(float2*)(out + (size_t)node * OUT_F + 2 * c) = make_float2(v0, v1);
    }
}

// ---------------------------------------------------------------------------
extern "C" void kernel_launch(void* const* d_in, const int* in_sizes, int n_in,
                              void* d_out, int out_size, void* d_ws, size_t ws_size,
                              hipStream_t stream) {
    const float* x    = (const float*)d_in[0];
    const int*   edge = (const int*)d_in[1];   // (2, E) int32 row-major
    const float* W    = (const float*)d_in[2];
    const float* a    = (const float*)d_in[3];
    float*       out  = (float*)d_out;

    const int* esrc = edge;
    const int* edst = edge + E_EDGES;

    char* ws = (char*)d_ws;
    size_t off = 0;
    __hip_bfloat16* hb = (__hip_bfloat16*)(ws + off); off += (size_t)N_NODES * OUT_F * 2; // 6.4MB
    float* s_src  = (float*)(ws + off); off += (size_t)N_NODES * 4;
    float* s_dst  = (float*)(ws + off); off += (size_t)N_NODES * 4;
    int*   rowptr = (int*)  (ws + off); off += (size_t)N_NODES * 4;
    int*   dcnt   = (int*)  (ws + off); off += (size_t)N_NODES * 4;
    int*   bcur   = (int*)  (ws + off); off += 256 * 4;
    unsigned* recs_tmp = (unsigned*)(ws + off); off += (size_t)NBKT * BKT_CAP * 4;  // 12.8MB
    int2*     recs     = (int2*)    (ws + off); off += (size_t)NBKT * BKT_CAP * 8;  // 25.6MB

    gat_init_cursors<<<1, 256, 0, stream>>>(bcur);

    gat_gemm_mfma<<<(N_NODES + 63) / 64, 256, 0, stream>>>(x, W, a, hb, s_src, s_dst);

    gat_bin<<<NBLK_BIN, 256, 0, stream>>>(esrc, edst, bcur, recs_tmp);

    gat_pass2<<<NBKT, 256, 0, stream>>>(bcur, recs_tmp, s_src, s_dst,
                                        rowptr, dcnt, recs);

    gat_aggregate<<<N_NODES / 4, 256, 0, stream>>>(rowptr, dcnt, recs, hb, out);
}

// Round 7
// 104.505 us; speedup vs baseline: 5.2974x; 1.2086x over previous
//
#include <hip/hip_runtime.h>
#include <hip/hip_bf16.h>

#define N_NODES 50000
#define E_EDGES 1600000
#define IN_F    128
#define OUT_F   64
#define ALPHA   0.2f

#define BKT_SHIFT 8
#define BKT_NODES 256
#define NBKT 196                 // ceil(50000/256)
#define BKT_CAP 16384            // per-bucket record capacity (mean 8192, 90 sigma)
#define CHUNK 4096               // edges per binning block
#define NBLK_BIN 391             // ceil(1600000/4096)

typedef __bf16 bf16x8 __attribute__((ext_vector_type(8)));
typedef float  f32x4  __attribute__((ext_vector_type(4)));

// ---------------------------------------------------------------------------
// K1: h = X @ W via MFMA 16x16x32 bf16. One wave per 16 rows x 64 cols.
// Fused epilogue computes s_src/s_dst from the fp32 accumulator.
// C/D layout: col = lane&15, row = (lane>>4)*4 + reg   [m89-verified]
// ---------------------------------------------------------------------------
__global__ void __launch_bounds__(256)
gat_gemm_mfma(const float* __restrict__ x, const float* __restrict__ W,
              const float* __restrict__ a,
              __hip_bfloat16* __restrict__ hb,
              float* __restrict__ s_src, float* __restrict__ s_dst) {
    int wave = threadIdx.x >> 6;
    int lane = threadIdx.x & 63;
    int r0 = blockIdx.x * 64 + wave * 16;
    if (r0 >= N_NODES) return;                    // 50000 = 781*64 + 16

    int col = lane & 15;
    int klo = (lane >> 4) * 8;

    bf16x8 bw[4][4];
#pragma unroll
    for (int t = 0; t < 4; ++t)
#pragma unroll
        for (int s = 0; s < 4; ++s)
#pragma unroll
            for (int j = 0; j < 8; ++j)
                bw[t][s][j] = (__bf16)W[(32 * s + klo + j) * OUT_F + 16 * t + col];

    const float* xr = x + ((size_t)(r0 + col)) * IN_F;
    bf16x8 aw[4];
#pragma unroll
    for (int s = 0; s < 4; ++s) {
        float4 v0 = *(const float4*)(xr + 32 * s + klo);
        float4 v1 = *(const float4*)(xr + 32 * s + klo + 4);
        aw[s][0] = (__bf16)v0.x; aw[s][1] = (__bf16)v0.y;
        aw[s][2] = (__bf16)v0.z; aw[s][3] = (__bf16)v0.w;
        aw[s][4] = (__bf16)v1.x; aw[s][5] = (__bf16)v1.y;
        aw[s][6] = (__bf16)v1.z; aw[s][7] = (__bf16)v1.w;
    }

    f32x4 acc0 = {0.f,0.f,0.f,0.f}, acc1 = {0.f,0.f,0.f,0.f};
    f32x4 acc2 = {0.f,0.f,0.f,0.f}, acc3 = {0.f,0.f,0.f,0.f};
#pragma unroll
    for (int s = 0; s < 4; ++s) {
        acc0 = __builtin_amdgcn_mfma_f32_16x16x32_bf16(aw[s], bw[0][s], acc0, 0, 0, 0);
        acc1 = __builtin_amdgcn_mfma_f32_16x16x32_bf16(aw[s], bw[1][s], acc1, 0, 0, 0);
        acc2 = __builtin_amdgcn_mfma_f32_16x16x32_bf16(aw[s], bw[2][s], acc2, 0, 0, 0);
        acc3 = __builtin_amdgcn_mfma_f32_16x16x32_bf16(aw[s], bw[3][s], acc3, 0, 0, 0);
    }

    int grp = lane >> 4;
#pragma unroll
    for (int reg = 0; reg < 4; ++reg) {
        size_t base = (size_t)(r0 + grp * 4 + reg) * OUT_F + col;
        hb[base +  0] = __float2bfloat16(acc0[reg]);
        hb[base + 16] = __float2bfloat16(acc1[reg]);
        hb[base + 32] = __float2bfloat16(acc2[reg]);
        hb[base + 48] = __float2bfloat16(acc3[reg]);
    }

    float as0 = a[col], as1 = a[16 + col], as2 = a[32 + col], as3 = a[48 + col];
    float ad0 = a[64 + col], ad1 = a[80 + col], ad2 = a[96 + col], ad3 = a[112 + col];
#pragma unroll
    for (int reg = 0; reg < 4; ++reg) {
        float ps = acc0[reg] * as0 + acc1[reg] * as1 + acc2[reg] * as2 + acc3[reg] * as3;
        float pd = acc0[reg] * ad0 + acc1[reg] * ad1 + acc2[reg] * ad2 + acc3[reg] * ad3;
#pragma unroll
        for (int off = 1; off < 16; off <<= 1) {
            ps += __shfl_xor(ps, off, 64);
            pd += __shfl_xor(pd, off, 64);
        }
        if (col == 0) {
            s_src[r0 + grp * 4 + reg] = ps;
            s_dst[r0 + grp * 4 + reg] = pd;
        }
    }
}

// ---------------------------------------------------------------------------
// K0: seed bucket cursors at fixed-stride region bases
// ---------------------------------------------------------------------------
__global__ void __launch_bounds__(256)
gat_init_cursors(int* __restrict__ bcur) {
    int t = threadIdx.x;
    if (t < NBKT) bcur[t] = t * BKT_CAP;
}

// ---------------------------------------------------------------------------
// K2: LDS counting-sort binning. Each block bins CHUNK edges by bucket
// (= src>>8) in LDS, reserves global space with ONE atomic per bucket,
// flushes contiguous runs -> full-line writes. Records are 4B (src<<16|dst).
// ---------------------------------------------------------------------------
__global__ void __launch_bounds__(256)
gat_bin(const int* __restrict__ esrc, const int* __restrict__ edst,
        int* __restrict__ bcur, unsigned* __restrict__ recs_tmp) {
    __shared__ unsigned recs_l[CHUNK];     // 16KB
    __shared__ int cnt[NBKT];
    __shared__ int start[256];
    __shared__ int gbase[NBKT];
    __shared__ int sc[256];

    int t = threadIdx.x;
    int ebase = blockIdx.x * CHUNK;

    if (t < NBKT) cnt[t] = 0;
    __syncthreads();

    unsigned rec[16];
    int      loc[16];
#pragma unroll
    for (int k = 0; k < 16; ++k) {
        int e = ebase + k * 256 + t;
        if (e < E_EDGES) {
            unsigned s = (unsigned)esrc[e];
            unsigned d = (unsigned)edst[e];
            rec[k] = (s << 16) | d;
            loc[k] = atomicAdd(&cnt[s >> BKT_SHIFT], 1);
        } else {
            loc[k] = -1;
            rec[k] = 0;
        }
    }
    __syncthreads();

    // exclusive scan of cnt -> start (Hillis-Steele over 256)
    int v = (t < NBKT) ? cnt[t] : 0;
    sc[t] = v;
    __syncthreads();
    for (int d = 1; d < 256; d <<= 1) {
        int add = (t >= d) ? sc[t - d] : 0;
        __syncthreads();
        sc[t] += add;
        __syncthreads();
    }
    start[t] = sc[t] - v;
    __syncthreads();

    // place records into LDS, bucket-grouped
#pragma unroll
    for (int k = 0; k < 16; ++k)
        if (loc[k] >= 0)
            recs_l[start[rec[k] >> 24] + loc[k]] = rec[k];

    // reserve global space, one atomic per bucket
    if (t < NBKT) {
        int c = cnt[t];
        gbase[t] = (c > 0) ? atomicAdd(&bcur[t], c) : 0;
    }
    __syncthreads();

    // flush: consecutive LDS slots -> consecutive global slots per bucket
    int total = min(CHUNK, E_EDGES - ebase);
    for (int i = t; i < total; i += 256) {
        unsigned r = recs_l[i];
        int b = r >> 24;
        int pos = gbase[b] + (i - start[b]);
        if (pos < (b + 1) * BKT_CAP)               // 90-sigma guard, never trips
            recs_tmp[pos] = r;
    }
}

// ---------------------------------------------------------------------------
// K3: per-bucket pass: LDS histogram of its 256 nodes -> rowptr/dcnt,
// then compute ee and place {dst, ee} sorted-by-src within the bucket's
// fixed-stride output region (64KB window, L2-resident writes).
// ---------------------------------------------------------------------------
__global__ void __launch_bounds__(256)
gat_pass2(const int* __restrict__ bcur, const unsigned* __restrict__ recs_tmp,
          const float* __restrict__ s_src, const float* __restrict__ s_dst,
          int* __restrict__ rowptr, int* __restrict__ dcnt,
          int2* __restrict__ recs) {
    __shared__ int ncnt[256];
    __shared__ int lcur[256];
    __shared__ int sc[256];

    int b = blockIdx.x;
    int t = threadIdx.x;
    int nbase = b << BKT_SHIFT;
    int rbase = b * BKT_CAP;
    int m = bcur[b] - rbase;                       // records in this bucket

    ncnt[t] = 0;
    __syncthreads();

    for (int i = t; i < m; i += 256) {
        unsigned r = recs_tmp[rbase + i];
        atomicAdd(&ncnt[(r >> 16) & (BKT_NODES - 1)], 1);
    }
    __syncthreads();

    // exclusive scan ncnt -> per-node start within bucket
    int v = ncnt[t];
    sc[t] = v;
    __syncthreads();
    for (int d = 1; d < 256; d <<= 1) {
        int add = (t >= d) ? sc[t - d] : 0;
        __syncthreads();
        sc[t] += add;
        __syncthreads();
    }
    int nstart = sc[t] - v;
    lcur[t] = nstart;
    int node = nbase + t;
    if (node < N_NODES) {
        rowptr[node] = rbase + nstart;             // positions in strided recs
        dcnt[node]   = v;
    }
    __syncthreads();

    for (int i = t; i < m; i += 256) {
        unsigned r = recs_tmp[rbase + i];
        int s = r >> 16;
        int d = r & 0xFFFF;
        float sco = s_src[s] + s_dst[d];
        float lr = sco > 0.f ? sco : ALPHA * sco;
        float ee = __expf(-lr);
        int idx = atomicAdd(&lcur[s & (BKT_NODES - 1)], 1);
        recs[rbase + idx] = make_int2(d, __float_as_int(ee));
    }
}

// ---------------------------------------------------------------------------
// K4: per-node segment reduction, register-staged records + quarter-wave
// gathers. One coalesced load stages up to 64 records into registers (lane i
// holds rec i); per-iteration record access is a __shfl (no load->load
// dependency). Quarter q (lanes 16q..16q+15) handles edge j = q*nq + k;
// each lane loads uint2 (4 bf16) -> 16 lanes = full 128B row, one gather
// instruction covers 4 edges. Cross-quarter merge via shfl_xor(16,32).
// ---------------------------------------------------------------------------
__global__ void __launch_bounds__(256)
gat_aggregate(const int* __restrict__ rowptr, const int* __restrict__ dcnt,
              const int2* __restrict__ recs,
              const __hip_bfloat16* __restrict__ hb, float* __restrict__ out) {
    int node = blockIdx.x * 4 + (threadIdx.x >> 6);   // 12500 blocks
    int lane = threadIdx.x & 63;
    int q = lane >> 4;               // quarter 0..3
    int c = lane & 15;               // feature group: features 4c..4c+3
    int beg = rowptr[node];
    int n   = dcnt[node];
    const uint2* hbu = (const uint2*)hb;   // row = dst*16 + c (8B granules)

    float a0 = 0.f, a1 = 0.f, a2 = 0.f, a3 = 0.f, rs = 0.f;

    for (int base = 0; base < n; base += 64) {
        int m = n - base; if (m > 64) m = 64;
        int2 rec = make_int2(0, 0);
        if (lane < m) rec = recs[beg + base + lane];  // coalesced stage
        int nq = (m + 3) >> 2;                        // edges per quarter
#pragma unroll 8
        for (int k = 0; k < nq; ++k) {
            int j = q * nq + k;                       // this quarter's edge
            int rx = __shfl(rec.x, j, 64);
            int ry = __shfl(rec.y, j, 64);
            float ee = (j < m) ? __int_as_float(ry) : 0.f;
            uint2 u = hbu[(unsigned)rx * 16 + c];
            float h0 = __uint_as_float(u.x << 16);
            float h1 = __uint_as_float(u.x & 0xffff0000u);
            float h2 = __uint_as_float(u.y << 16);
            float h3 = __uint_as_float(u.y & 0xffff0000u);
            a0 += ee * h0;
            a1 += ee * h1;
            a2 += ee * h2;
            a3 += ee * h3;
            rs += ee;
        }
    }

    // merge quarters (lanes sharing c): xor 16 then 32
    a0 += __shfl_xor(a0, 16, 64); a0 += __shfl_xor(a0, 32, 64);
    a1 += __shfl_xor(a1, 16, 64); a1 += __shfl_xor(a1, 32, 64);
    a2 += __shfl_xor(a2, 16, 64); a2 += __shfl_xor(a2, 32, 64);
    a3 += __shfl_xor(a3, 16, 64); a3 += __shfl_xor(a3, 32, 64);
    rs += __shfl_xor(rs, 16, 64); rs += __shfl_xor(rs, 32, 64);

    if (q == 0) {
        float inv = (rs != 0.f) ? 1.f / rs : 0.f;
        float v0 = a0 * inv, v1 = a1 * inv, v2 = a2 * inv, v3 = a3 * inv;
        v0 = v0 > 0.f ? v0 : (__expf(v0) - 1.f);
        v1 = v1 > 0.f ? v1 : (__expf(v1) - 1.f);
        v2 = v2 > 0.f ? v2 : (__expf(v2) - 1.f);
        v3 = v3 > 0.f ? v3 : (__expf(v3) - 1.f);
        *(float4*)(out + (size_t)node * OUT_F + 4 * c) =
            make_float4(v0, v1, v2, v3);
    }
}

// ---------------------------------------------------------------------------
extern "C" void kernel_launch(void* const* d_in, const int* in_sizes, int n_in,
                              void* d_out, int out_size, void* d_ws, size_t ws_size,
                              hipStream_t stream) {
    const float* x    = (const float*)d_in[0];
    const int*   edge = (const int*)d_in[1];   // (2, E) int32 row-major
    const float* W    = (const float*)d_in[2];
    const float* a    = (const float*)d_in[3];
    float*       out  = (float*)d_out;

    const int* esrc = edge;
    const int* edst = edge + E_EDGES;

    char* ws = (char*)d_ws;
    size_t off = 0;
    __hip_bfloat16* hb = (__hip_bfloat16*)(ws + off); off += (size_t)N_NODES * OUT_F * 2; // 6.4MB
    float* s_src  = (float*)(ws + off); off += (size_t)N_NODES * 4;
    float* s_dst  = (float*)(ws + off); off += (size_t)N_NODES * 4;
    int*   rowptr = (int*)  (ws + off); off += (size_t)N_NODES * 4;
    int*   dcnt   = (int*)  (ws + off); off += (size_t)N_NODES * 4;
    int*   bcur   = (int*)  (ws + off); off += 256 * 4;
    unsigned* recs_tmp = (unsigned*)(ws + off); off += (size_t)NBKT * BKT_CAP * 4;  // 12.8MB
    int2*     recs     = (int2*)    (ws + off); off += (size_t)NBKT * BKT_CAP * 8;  // 25.6MB

    gat_init_cursors<<<1, 256, 0, stream>>>(bcur);

    gat_gemm_mfma<<<(N_NODES + 63) / 64, 256, 0, stream>>>(x, W, a, hb, s_src, s_dst);

    gat_bin<<<NBLK_BIN, 256, 0, stream>>>(esrc, edst, bcur, recs_tmp);

    gat_pass2<<<NBKT, 256, 0, stream>>>(bcur, recs_tmp, s_src, s_dst,
                                        rowptr, dcnt, recs);

    gat_aggregate<<<N_NODES / 4, 256, 0, stream>>>(rowptr, dcnt, recs, hb, out);
}

// Round 8
// 87.301 us; speedup vs baseline: 6.3413x; 1.1971x over previous
//
#include <hip/hip_runtime.h>
#include <hip/hip_bf16.h>

#define N_NODES 50000
#define E_EDGES 1600000
#define IN_F    128
#define OUT_F   64
#define ALPHA   0.2f

#define BKT_SHIFT 8
#define BKT_NODES 256
#define NBKT 196                 // ceil(50000/256)
#define BKT_CAP 16384            // per-bucket record capacity (mean 8192, 90 sigma)
#define CHUNK 4096               // edges per binning block
#define NBLK_BIN 391             // ceil(1600000/4096)
#define NBLK_GEMM 782            // ceil(50000/64)

typedef __bf16 bf16x8 __attribute__((ext_vector_type(8)));
typedef float  f32x4  __attribute__((ext_vector_type(4)));

// round-to-nearest-even f32 -> bf16 bits
__device__ __forceinline__ unsigned f32_to_bf16_bits(float f) {
    unsigned u = __float_as_uint(f);
    return (u + 0x7FFFu + ((u >> 16) & 1u)) >> 16;
}

// ---------------------------------------------------------------------------
// K1 fused: blocks [0, NBLK_GEMM) run the MFMA GEMM (h = X@W + scores);
// blocks [NBLK_GEMM, NBLK_GEMM+NBLK_BIN) run the LDS counting-sort binning.
// Independent work fused to overlap compute-bound gemm with memory-bound bin.
// ---------------------------------------------------------------------------
__global__ void __launch_bounds__(256)
gat_gemm_bin(const float* __restrict__ x, const float* __restrict__ W,
             const float* __restrict__ a,
             __hip_bfloat16* __restrict__ hb,
             float* __restrict__ s_src, float* __restrict__ s_dst,
             const int* __restrict__ esrc, const int* __restrict__ edst,
             int* __restrict__ bcur, unsigned* __restrict__ recs_tmp) {
    if (blockIdx.x < NBLK_GEMM) {
        // ---- GEMM: one wave per 16 rows x 64 cols.
        // C/D layout: col = lane&15, row = (lane>>4)*4 + reg   [m89-verified]
        int wave = threadIdx.x >> 6;
        int lane = threadIdx.x & 63;
        int r0 = blockIdx.x * 64 + wave * 16;
        if (r0 >= N_NODES) return;                // 50000 = 781*64 + 16

        int col = lane & 15;
        int klo = (lane >> 4) * 8;

        bf16x8 bw[4][4];
#pragma unroll
        for (int t = 0; t < 4; ++t)
#pragma unroll
            for (int s = 0; s < 4; ++s)
#pragma unroll
                for (int j = 0; j < 8; ++j)
                    bw[t][s][j] = (__bf16)W[(32 * s + klo + j) * OUT_F + 16 * t + col];

        const float* xr = x + ((size_t)(r0 + col)) * IN_F;
        bf16x8 aw[4];
#pragma unroll
        for (int s = 0; s < 4; ++s) {
            float4 v0 = *(const float4*)(xr + 32 * s + klo);
            float4 v1 = *(const float4*)(xr + 32 * s + klo + 4);
            aw[s][0] = (__bf16)v0.x; aw[s][1] = (__bf16)v0.y;
            aw[s][2] = (__bf16)v0.z; aw[s][3] = (__bf16)v0.w;
            aw[s][4] = (__bf16)v1.x; aw[s][5] = (__bf16)v1.y;
            aw[s][6] = (__bf16)v1.z; aw[s][7] = (__bf16)v1.w;
        }

        f32x4 acc0 = {0.f,0.f,0.f,0.f}, acc1 = {0.f,0.f,0.f,0.f};
        f32x4 acc2 = {0.f,0.f,0.f,0.f}, acc3 = {0.f,0.f,0.f,0.f};
#pragma unroll
        for (int s = 0; s < 4; ++s) {
            acc0 = __builtin_amdgcn_mfma_f32_16x16x32_bf16(aw[s], bw[0][s], acc0, 0, 0, 0);
            acc1 = __builtin_amdgcn_mfma_f32_16x16x32_bf16(aw[s], bw[1][s], acc1, 0, 0, 0);
            acc2 = __builtin_amdgcn_mfma_f32_16x16x32_bf16(aw[s], bw[2][s], acc2, 0, 0, 0);
            acc3 = __builtin_amdgcn_mfma_f32_16x16x32_bf16(aw[s], bw[3][s], acc3, 0, 0, 0);
        }

        int grp = lane >> 4;
#pragma unroll
        for (int reg = 0; reg < 4; ++reg) {
            size_t base = (size_t)(r0 + grp * 4 + reg) * OUT_F + col;
            hb[base +  0] = __float2bfloat16(acc0[reg]);
            hb[base + 16] = __float2bfloat16(acc1[reg]);
            hb[base + 32] = __float2bfloat16(acc2[reg]);
            hb[base + 48] = __float2bfloat16(acc3[reg]);
        }

        float as0 = a[col], as1 = a[16 + col], as2 = a[32 + col], as3 = a[48 + col];
        float ad0 = a[64 + col], ad1 = a[80 + col], ad2 = a[96 + col], ad3 = a[112 + col];
#pragma unroll
        for (int reg = 0; reg < 4; ++reg) {
            float ps = acc0[reg] * as0 + acc1[reg] * as1 + acc2[reg] * as2 + acc3[reg] * as3;
            float pd = acc0[reg] * ad0 + acc1[reg] * ad1 + acc2[reg] * ad2 + acc3[reg] * ad3;
#pragma unroll
            for (int off = 1; off < 16; off <<= 1) {
                ps += __shfl_xor(ps, off, 64);
                pd += __shfl_xor(pd, off, 64);
            }
            if (col == 0) {
                s_src[r0 + grp * 4 + reg] = ps;
                s_dst[r0 + grp * 4 + reg] = pd;
            }
        }
    } else {
        // ---- BIN: LDS counting-sort of CHUNK edges by bucket (src>>8).
        // One global atomic per (block,bucket); flush = contiguous runs.
        __shared__ unsigned recs_l[CHUNK];     // 16KB
        __shared__ int cnt[NBKT];
        __shared__ int start[256];
        __shared__ int gbase[NBKT];
        __shared__ int sc[256];

        int t = threadIdx.x;
        int ebase = (blockIdx.x - NBLK_GEMM) * CHUNK;

        if (t < NBKT) cnt[t] = 0;
        __syncthreads();

        unsigned rec[16];
        int      loc[16];
#pragma unroll
        for (int k = 0; k < 16; ++k) {
            int e = ebase + k * 256 + t;
            if (e < E_EDGES) {
                unsigned s = (unsigned)esrc[e];
                unsigned d = (unsigned)edst[e];
                rec[k] = (s << 16) | d;
                loc[k] = atomicAdd(&cnt[s >> BKT_SHIFT], 1);
            } else {
                loc[k] = -1;
                rec[k] = 0;
            }
        }
        __syncthreads();

        int v = (t < NBKT) ? cnt[t] : 0;
        sc[t] = v;
        __syncthreads();
        for (int d = 1; d < 256; d <<= 1) {
            int add = (t >= d) ? sc[t - d] : 0;
            __syncthreads();
            sc[t] += add;
            __syncthreads();
        }
        start[t] = sc[t] - v;
        __syncthreads();

#pragma unroll
        for (int k = 0; k < 16; ++k)
            if (loc[k] >= 0)
                recs_l[start[rec[k] >> 24] + loc[k]] = rec[k];

        if (t < NBKT) {
            int c = cnt[t];
            gbase[t] = (c > 0) ? atomicAdd(&bcur[t], c) : 0;
        }
        __syncthreads();

        int total = min(CHUNK, E_EDGES - ebase);
        for (int i = t; i < total; i += 256) {
            unsigned r = recs_l[i];
            int b = r >> 24;
            int pos = gbase[b] + (i - start[b]);
            if (pos < (b + 1) * BKT_CAP)           // 90-sigma guard, never trips
                recs_tmp[pos] = r;
        }
    }
}

// ---------------------------------------------------------------------------
// K0: seed bucket cursors at fixed-stride region bases
// ---------------------------------------------------------------------------
__global__ void __launch_bounds__(256)
gat_init_cursors(int* __restrict__ bcur) {
    int t = threadIdx.x;
    if (t < NBKT) bcur[t] = t * BKT_CAP;
}

// ---------------------------------------------------------------------------
// K3: per-bucket pass, 1024 threads (16 waves/CU vs 4 before): LDS histogram
// -> rowptr/dcnt, then compute ee and place 4B records {dst:16 | ee:bf16}
// sorted-by-src within the bucket's fixed-stride region (L2-resident).
// ---------------------------------------------------------------------------
__global__ void __launch_bounds__(1024)
gat_pass2(const int* __restrict__ bcur, const unsigned* __restrict__ recs_tmp,
          const float* __restrict__ s_src, const float* __restrict__ s_dst,
          int* __restrict__ rowptr, int* __restrict__ dcnt,
          unsigned* __restrict__ recs) {
    __shared__ int ncnt[256];
    __shared__ int lcur[256];
    __shared__ int sc[256];

    int b = blockIdx.x;
    int t = threadIdx.x;
    int nbase = b << BKT_SHIFT;
    int rbase = b * BKT_CAP;
    int m = bcur[b] - rbase;                       // records in this bucket

    if (t < 256) ncnt[t] = 0;
    __syncthreads();

    for (int i = t; i < m; i += 1024) {
        unsigned r = recs_tmp[rbase + i];
        atomicAdd(&ncnt[(r >> 16) & (BKT_NODES - 1)], 1);
    }
    __syncthreads();

    // exclusive scan ncnt -> per-node start (threads 0-255 active; all sync)
    int v = 0;
    if (t < 256) { v = ncnt[t]; sc[t] = v; }
    __syncthreads();
    for (int d = 1; d < 256; d <<= 1) {
        int add = 0;
        if (t < 256 && t >= d) add = sc[t - d];
        __syncthreads();
        if (t < 256) sc[t] += add;
        __syncthreads();
    }
    if (t < 256) {
        int nstart = sc[t] - v;
        lcur[t] = nstart;
        int node = nbase + t;
        if (node < N_NODES) {
            rowptr[node] = rbase + nstart;
            dcnt[node]   = v;
        }
    }
    __syncthreads();

    for (int i = t; i < m; i += 1024) {
        unsigned r = recs_tmp[rbase + i];
        int s = r >> 16;
        int d = r & 0xFFFF;
        float sco = s_src[s] + s_dst[d];
        float lr = sco > 0.f ? sco : ALPHA * sco;
        float ee = __expf(-lr);
        int idx = atomicAdd(&lcur[s & (BKT_NODES - 1)], 1);
        recs[rbase + idx] = ((unsigned)d << 16) | f32_to_bf16_bits(ee);
    }
}

// ---------------------------------------------------------------------------
// K4: per-node segment reduction, register-staged 4B records + quarter-wave
// gathers. One coalesced load stages up to 64 records (lane i holds rec i);
// per-iteration record access is one __shfl. Quarter q handles edge
// j = q*nq + k; each lane loads uint2 (4 bf16) -> 16 lanes = full 128B row.
// ---------------------------------------------------------------------------
__global__ void __launch_bounds__(256)
gat_aggregate(const int* __restrict__ rowptr, const int* __restrict__ dcnt,
              const unsigned* __restrict__ recs,
              const __hip_bfloat16* __restrict__ hb, float* __restrict__ out) {
    int node = blockIdx.x * 4 + (threadIdx.x >> 6);   // 12500 blocks
    int lane = threadIdx.x & 63;
    int q = lane >> 4;               // quarter 0..3
    int c = lane & 15;               // feature group: features 4c..4c+3
    int beg = rowptr[node];
    int n   = dcnt[node];
    const uint2* hbu = (const uint2*)hb;   // row = dst*16 + c (8B granules)

    float a0 = 0.f, a1 = 0.f, a2 = 0.f, a3 = 0.f, rs = 0.f;

    for (int base = 0; base < n; base += 64) {
        int m = n - base; if (m > 64) m = 64;
        unsigned rec = 0;
        if (lane < m) rec = recs[beg + base + lane];  // coalesced stage
        int nq = (m + 3) >> 2;                        // edges per quarter
#pragma unroll 8
        for (int k = 0; k < nq; ++k) {
            int j = q * nq + k;                       // this quarter's edge
            unsigned r = (unsigned)__shfl((int)rec, j, 64);
            float ee = (j < m) ? __uint_as_float((r & 0xFFFFu) << 16) : 0.f;
            uint2 u = hbu[(r >> 16) * 16 + c];
            float h0 = __uint_as_float(u.x << 16);
            float h1 = __uint_as_float(u.x & 0xffff0000u);
            float h2 = __uint_as_float(u.y << 16);
            float h3 = __uint_as_float(u.y & 0xffff0000u);
            a0 += ee * h0;
            a1 += ee * h1;
            a2 += ee * h2;
            a3 += ee * h3;
            rs += ee;
        }
    }

    // merge quarters (lanes sharing c): xor 16 then 32
    a0 += __shfl_xor(a0, 16, 64); a0 += __shfl_xor(a0, 32, 64);
    a1 += __shfl_xor(a1, 16, 64); a1 += __shfl_xor(a1, 32, 64);
    a2 += __shfl_xor(a2, 16, 64); a2 += __shfl_xor(a2, 32, 64);
    a3 += __shfl_xor(a3, 16, 64); a3 += __shfl_xor(a3, 32, 64);
    rs += __shfl_xor(rs, 16, 64); rs += __shfl_xor(rs, 32, 64);

    if (q == 0) {
        float inv = (rs != 0.f) ? 1.f / rs : 0.f;
        float v0 = a0 * inv, v1 = a1 * inv, v2 = a2 * inv, v3 = a3 * inv;
        v0 = v0 > 0.f ? v0 : (__expf(v0) - 1.f);
        v1 = v1 > 0.f ? v1 : (__expf(v1) - 1.f);
        v2 = v2 > 0.f ? v2 : (__expf(v2) - 1.f);
        v3 = v3 > 0.f ? v3 : (__expf(v3) - 1.f);
        *(float4*)(out + (size_t)node * OUT_F + 4 * c) =
            make_float4(v0, v1, v2, v3);
    }
}

// ---------------------------------------------------------------------------
extern "C" void kernel_launch(void* const* d_in, const int* in_sizes, int n_in,
                              void* d_out, int out_size, void* d_ws, size_t ws_size,
                              hipStream_t stream) {
    const float* x    = (const float*)d_in[0];
    const int*   edge = (const int*)d_in[1];   // (2, E) int32 row-major
    const float* W    = (const float*)d_in[2];
    const float* a    = (const float*)d_in[3];
    float*       out  = (float*)d_out;

    const int* esrc = edge;
    const int* edst = edge + E_EDGES;

    char* ws = (char*)d_ws;
    size_t off = 0;
    __hip_bfloat16* hb = (__hip_bfloat16*)(ws + off); off += (size_t)N_NODES * OUT_F * 2; // 6.4MB
    float* s_src  = (float*)(ws + off); off += (size_t)N_NODES * 4;
    float* s_dst  = (float*)(ws + off); off += (size_t)N_NODES * 4;
    int*   rowptr = (int*)  (ws + off); off += (size_t)N_NODES * 4;
    int*   dcnt   = (int*)  (ws + off); off += (size_t)N_NODES * 4;
    int*   bcur   = (int*)  (ws + off); off += 256 * 4;
    unsigned* recs_tmp = (unsigned*)(ws + off); off += (size_t)NBKT * BKT_CAP * 4;  // 12.8MB
    unsigned* recs     = (unsigned*)(ws + off); off += (size_t)NBKT * BKT_CAP * 4;  // 12.8MB

    gat_init_cursors<<<1, 256, 0, stream>>>(bcur);

    gat_gemm_bin<<<NBLK_GEMM + NBLK_BIN, 256, 0, stream>>>(
        x, W, a, hb, s_src, s_dst, esrc, edst, bcur, recs_tmp);

    gat_pass2<<<NBKT, 1024, 0, stream>>>(bcur, recs_tmp, s_src, s_dst,
                                         rowptr, dcnt, recs);

    gat_aggregate<<<N_NODES / 4, 256, 0, stream>>>(rowptr, dcnt, recs, hb, out);
}